// Round 7
// baseline (48.622 us; speedup 1.0000x reference)
//
#include <hip/hip_runtime.h>
#include <hip/hip_bf16.h>

// Problem constants
#define B 64
#define D 1024
#define H 1024
#define C 32           // chunks along D
#define L (D / C)      // chunk length = 32
#define BG 4           // batch rows per block (register-shared weight loads)
#define NBG (B / BG)   // 16 batch groups
#define HQ 4           // h-quarters
#define HP (H / HQ)    // 256 h per block = 1 h per thread

// DPP quad-perm cross-lane (VALU-speed, no LDS)
__device__ __forceinline__ float dpp_xor1(float v) {
    int i = __builtin_bit_cast(int, v);
    i = __builtin_amdgcn_mov_dpp(i, 0xB1, 0xF, 0xF, true);  // quad_perm [1,0,3,2]
    return __builtin_bit_cast(float, i);
}
__device__ __forceinline__ float dpp_xor2(float v) {
    int i = __builtin_bit_cast(int, v);
    i = __builtin_amdgcn_mov_dpp(i, 0x4E, 0xF, 0xF, true);  // quad_perm [2,3,0,1]
    return __builtin_bit_cast(float, i);
}

// ---------------------------------------------------------------------------
// Kernel 1: per-chunk rank-1 sums, reading in_W [H,D] DIRECTLY (no transpose).
// block = (bg, c, hq); thread owns one h; in_W[h][cL..cL+31] is contiguous ->
// 8x float4 preload into registers; 4 batch rows share them.
// S[b,c,h] = sum_{j in chunk c} x[b,j]*in_W[h, cL+j]
// ---------------------------------------------------------------------------
__global__ void __launch_bounds__(256)
k_chunk_sums(const float* __restrict__ x,
             const float* __restrict__ in_W,
             float* __restrict__ S) {
    int blk = blockIdx.x;
    int bg  = blk >> 7;          // /128
    int chq = blk & 127;
    int c   = chq >> 2;
    int hq  = chq & 3;
    int b0  = bg * BG;
    int tid = threadIdx.x;
    int h   = hq * HP + tid;

    __shared__ float4 xs4[L];
    if (tid < L) {
        int i = c * L + tid;
        xs4[tid] = make_float4(x[(size_t)b0 * D + i],
                               x[(size_t)(b0 + 1) * D + i],
                               x[(size_t)(b0 + 2) * D + i],
                               x[(size_t)(b0 + 3) * D + i]);
    }

    // per-thread contiguous row-slice preload (fully-used 64B lines)
    const float* wrow = &in_W[(size_t)h * D + c * L];
    float wr[L];
    #pragma unroll
    for (int q = 0; q < L / 4; ++q)
        *reinterpret_cast<float4*>(&wr[q * 4]) =
            *reinterpret_cast<const float4*>(wrow + q * 4);

    __syncthreads();

    float acc0 = 0.f, acc1 = 0.f, acc2 = 0.f, acc3 = 0.f;
    #pragma unroll
    for (int j = 0; j < L; ++j) {
        float4 xf = xs4[j];
        float w = wr[j];
        acc0 = fmaf(xf.x, w, acc0);
        acc1 = fmaf(xf.y, w, acc1);
        acc2 = fmaf(xf.z, w, acc2);
        acc3 = fmaf(xf.w, w, acc3);
    }
    S[((size_t)b0 * C + c) * H + h]       = acc0;
    S[((size_t)(b0 + 1) * C + c) * H + h] = acc1;
    S[((size_t)(b0 + 2) * C + c) * H + h] = acc2;
    S[((size_t)(b0 + 3) * C + c) * H + h] = acc3;
}

// ---------------------------------------------------------------------------
// Kernel 2: main NADE chain with FUSED prefix-scan (reads raw chunk sums S).
// block = (bg, c, hq); thread owns one h; 4 batch rows per thread.
// Prefix: a_b = in_b[h] + sum_{c'<c} S[b,c',h] (coalesced one-time loads).
// Loop: barrier-free; h_W load (coalesced) + register wt row cache;
// quad-DPP reduce + keeper-lane stash; predicated FMA recurrence.
// Writes per-quarter partial dots Q[hq][b][d].
// ---------------------------------------------------------------------------
__global__ void __launch_bounds__(256, 2)
k_nade_main(const float* __restrict__ x,
            const float* __restrict__ in_W,
            const float* __restrict__ in_b,
            const float* __restrict__ h_W,
            const float* __restrict__ S,   // raw per-chunk sums [B,C,H]
            float* __restrict__ Q) {       // [HQ][B][D] partial dots
    int blk = blockIdx.x;
    int bg  = blk >> 7;
    int chq = blk & 127;
    int c   = chq >> 2;
    int hq  = chq & 3;
    int b0  = bg * BG;
    int tid = threadIdx.x;
    int h   = hq * HP + tid;
    int lane = tid & 63;
    int wv = tid >> 6;
    int ph = lane & 3;

    __shared__ float4 xs4[L];
    if (tid < L) {
        int i = c * L + tid;
        xs4[tid] = make_float4(x[(size_t)b0 * D + i],
                               x[(size_t)(b0 + 1) * D + i],
                               x[(size_t)(b0 + 2) * D + i],
                               x[(size_t)(b0 + 3) * D + i]);
    }

    // register row cache of in_W[h][cL..cL+31] (contiguous)
    const float* wrow = &in_W[(size_t)h * D + c * L];
    float wr[L];
    #pragma unroll
    for (int q = 0; q < L / 4; ++q)
        *reinterpret_cast<float4*>(&wr[q * 4]) =
            *reinterpret_cast<const float4*>(wrow + q * 4);

    // fused exclusive prefix over chunks (coalesced across threads)
    float ib = in_b[h];
    float a0 = ib, a1 = ib, a2 = ib, a3 = ib;
    for (int cc = 0; cc < c; ++cc) {
        a0 += S[((size_t)b0 * C + cc) * H + h];
        a1 += S[((size_t)(b0 + 1) * C + cc) * H + h];
        a2 += S[((size_t)(b0 + 2) * C + cc) * H + h];
        a3 += S[((size_t)(b0 + 3) * C + cc) * H + h];
    }

    __syncthreads();

    bool k0 = (ph == 0), k1 = (ph == 1), k2 = (ph == 2), k3 = (ph == 3);

    float pr0[8], pr1[8], pr2[8], pr3[8];
    #pragma unroll
    for (int s = 0; s < 8; ++s) { pr0[s] = 0.f; pr1[s] = 0.f; pr2[s] = 0.f; pr3[s] = 0.f; }

    #pragma unroll
    for (int il = 0; il < L; ++il) {
        int i = c * L + il;
        float w  = h_W[(size_t)i * H + h];
        float wt = wr[il];
        float4 xf = xs4[il];
        int s = il >> 2;
        bool keep = (il & 3) == 0 ? k0 : ((il & 3) == 1 ? k1 : ((il & 3) == 2 ? k2 : k3));

        float p0 = fmaxf(a0, 0.f) * w;
        float t0 = p0 + dpp_xor1(p0); t0 = t0 + dpp_xor2(t0);
        pr0[s] = keep ? t0 : pr0[s];
        a0 = fmaf(xf.x, wt, a0);

        float p1 = fmaxf(a1, 0.f) * w;
        float t1 = p1 + dpp_xor1(p1); t1 = t1 + dpp_xor2(t1);
        pr1[s] = keep ? t1 : pr1[s];
        a1 = fmaf(xf.y, wt, a1);

        float p2 = fmaxf(a2, 0.f) * w;
        float t2 = p2 + dpp_xor1(p2); t2 = t2 + dpp_xor2(t2);
        pr2[s] = keep ? t2 : pr2[s];
        a2 = fmaf(xf.z, wt, a2);

        float p3 = fmaxf(a3, 0.f) * w;
        float t3 = p3 + dpp_xor1(p3); t3 = t3 + dpp_xor2(t3);
        pr3[s] = keep ? t3 : pr3[s];
        a3 = fmaf(xf.w, wt, a3);
    }

    // cross-quad reduce within the wave (sum over 16 quads = 64 h)
    #pragma unroll
    for (int s = 0; s < 8; ++s) {
        float v;
        v = pr0[s];
        v += __shfl_xor(v, 4, 64); v += __shfl_xor(v, 8, 64);
        v += __shfl_xor(v, 16, 64); v += __shfl_xor(v, 32, 64);
        pr0[s] = v;
        v = pr1[s];
        v += __shfl_xor(v, 4, 64); v += __shfl_xor(v, 8, 64);
        v += __shfl_xor(v, 16, 64); v += __shfl_xor(v, 32, 64);
        pr1[s] = v;
        v = pr2[s];
        v += __shfl_xor(v, 4, 64); v += __shfl_xor(v, 8, 64);
        v += __shfl_xor(v, 16, 64); v += __shfl_xor(v, 32, 64);
        pr2[s] = v;
        v = pr3[s];
        v += __shfl_xor(v, 4, 64); v += __shfl_xor(v, 8, 64);
        v += __shfl_xor(v, 16, 64); v += __shfl_xor(v, 32, 64);
        pr3[s] = v;
    }

    __shared__ float red[4][BG][L];
    if (lane < 4) {
        #pragma unroll
        for (int s = 0; s < 8; ++s) {
            red[wv][0][s * 4 + lane] = pr0[s];
            red[wv][1][s * 4 + lane] = pr1[s];
            red[wv][2][s * 4 + lane] = pr2[s];
            red[wv][3][s * 4 + lane] = pr3[s];
        }
    }
    __syncthreads();

    if (tid < BG * L) {
        int b = tid >> 5;
        int il = tid & 31;
        float t = red[0][b][il] + red[1][b][il] + red[2][b][il] + red[3][b][il];
        Q[((size_t)hq * B + (b0 + b)) * D + c * L + il] = t;
    }
}

// ---------------------------------------------------------------------------
// Kernel 3: combine h-quarter partials + bias + sigmoid
// ---------------------------------------------------------------------------
__global__ void __launch_bounds__(256)
k_combine(const float* __restrict__ Q,
          const float* __restrict__ h_b,
          float* __restrict__ out) {
    int idx = blockIdx.x * blockDim.x + threadIdx.x;  // 0 .. B*D-1
    if (idx >= B * D) return;
    int d = idx & (D - 1);
    float t = Q[idx] + Q[(size_t)B * D + idx] + Q[2 * (size_t)B * D + idx]
            + Q[3 * (size_t)B * D + idx] + h_b[d];
    out[idx] = 1.0f / (1.0f + expf(-t));
}

// ---------------------------------------------------------------------------
extern "C" void kernel_launch(void* const* d_in, const int* in_sizes, int n_in,
                              void* d_out, int out_size, void* d_ws, size_t ws_size,
                              hipStream_t stream) {
    const float* x    = (const float*)d_in[0];  // [B, D]
    const float* in_W = (const float*)d_in[1];  // [H, D]
    const float* in_b = (const float*)d_in[2];  // [H]
    const float* h_W  = (const float*)d_in[3];  // [D, H]
    const float* h_b  = (const float*)d_in[4];  // [D]
    float* out = (float*)d_out;                 // [B, D]

    float* S = (float*)d_ws;                    // [B, C, H]   8 MB
    float* Q = S + (size_t)B * C * H;           // [HQ, B, D]  1 MB

    // 1: chunk sums (direct in_W read, register row cache)
    k_chunk_sums<<<NBG * C * HQ, 256, 0, stream>>>(x, in_W, S);

    // 2: main chain (fused prefix scan + register row cache)
    k_nade_main<<<NBG * C * HQ, 256, 0, stream>>>(x, in_W, in_b, h_W, S, Q);

    // 3: combine quarters + sigmoid
    k_combine<<<(B * D + 255) / 256, 256, 0, stream>>>(Q, h_b, out);
}

// Round 8
// 44.241 us; speedup vs baseline: 1.0990x; 1.0990x over previous
//
#include <hip/hip_runtime.h>
#include <hip/hip_bf16.h>

// Problem constants
#define B 64
#define D 1024
#define H 1024
#define C 32           // chunks along D
#define L (D / C)      // chunk length = 32
#define BG 4           // batch rows per block (register-shared weight loads)
#define NBG (B / NBG_DUMMY)
#undef NBG
#define NBG (B / BG)   // 16 batch groups
#define HQ 4           // h-quarters
#define HP (H / HQ)    // 256 h per block = 1 h per thread

// DPP quad-perm cross-lane (VALU-speed, no LDS)
__device__ __forceinline__ float dpp_xor1(float v) {
    int i = __builtin_bit_cast(int, v);
    i = __builtin_amdgcn_mov_dpp(i, 0xB1, 0xF, 0xF, true);  // quad_perm [1,0,3,2]
    return __builtin_bit_cast(float, i);
}
__device__ __forceinline__ float dpp_xor2(float v) {
    int i = __builtin_bit_cast(int, v);
    i = __builtin_amdgcn_mov_dpp(i, 0x4E, 0xF, 0xF, true);  // quad_perm [2,3,0,1]
    return __builtin_bit_cast(float, i);
}

// Cooperative, coalesced load of in_W[hq*256 .. +255][c*32 .. +31] into LDS,
// transposed: wt[d_local][h_local]. Lanes 0..31 read 32 consecutive floats
// (fully-coalesced 128B segments); LDS write is 2-way banked (free).
__device__ __forceinline__ void load_wt_tile(const float* __restrict__ in_W,
                                             int hq, int c, int tid,
                                             float (*wt)[HP + 2]) {
    const float* base = in_W + (size_t)(hq * HP) * D + c * L;
    int col = tid & 31;         // d within chunk
    int rg  = tid >> 5;         // row sub-group 0..7
    #pragma unroll
    for (int r = 0; r < 32; ++r) {
        int row = r * 8 + rg;   // h_local 0..255
        wt[col][row] = base[(size_t)row * D + col];
    }
}

// ---------------------------------------------------------------------------
// Kernel 1: per-chunk rank-1 sums. block = (bg, c, hq); thread owns one h;
// 4 batch rows share LDS-transposed weights.
// S[b,c,h] = sum_{j in chunk c} x[b,j]*in_W[h, cL+j]
// ---------------------------------------------------------------------------
__global__ void __launch_bounds__(256)
k_chunk_sums(const float* __restrict__ x,
             const float* __restrict__ in_W,
             float* __restrict__ S) {
    int blk = blockIdx.x;
    int bg  = blk >> 7;          // /128
    int chq = blk & 127;
    int c   = chq >> 2;
    int hq  = chq & 3;
    int b0  = bg * BG;
    int tid = threadIdx.x;
    int h   = hq * HP + tid;

    __shared__ float wt[L][HP + 2];
    __shared__ float4 xs4[L];

    if (tid < L) {
        int i = c * L + tid;
        xs4[tid] = make_float4(x[(size_t)b0 * D + i],
                               x[(size_t)(b0 + 1) * D + i],
                               x[(size_t)(b0 + 2) * D + i],
                               x[(size_t)(b0 + 3) * D + i]);
    }
    load_wt_tile(in_W, hq, c, tid, wt);
    __syncthreads();

    float acc0 = 0.f, acc1 = 0.f, acc2 = 0.f, acc3 = 0.f;
    #pragma unroll
    for (int j = 0; j < L; ++j) {
        float w = wt[j][tid];
        float4 xf = xs4[j];
        acc0 = fmaf(xf.x, w, acc0);
        acc1 = fmaf(xf.y, w, acc1);
        acc2 = fmaf(xf.z, w, acc2);
        acc3 = fmaf(xf.w, w, acc3);
    }
    S[((size_t)b0 * C + c) * H + h]       = acc0;
    S[((size_t)(b0 + 1) * C + c) * H + h] = acc1;
    S[((size_t)(b0 + 2) * C + c) * H + h] = acc2;
    S[((size_t)(b0 + 3) * C + c) * H + h] = acc3;
}

// ---------------------------------------------------------------------------
// Kernel 2: main NADE chain with fused prefix-scan. block = (bg, c, hq);
// thread owns one h; 4 batch rows per thread. c is REVERSED in the block
// index so long-prefix blocks launch first (tail balance).
// Inner loop is barrier-free: h_W coalesced stream + LDS wt reads,
// quad-DPP reduce + keeper-lane stash, predicated FMA recurrence.
// Writes per-quarter partial dots Q[hq][b][d].
// ---------------------------------------------------------------------------
__global__ void __launch_bounds__(256)
k_nade_main(const float* __restrict__ x,
            const float* __restrict__ in_W,
            const float* __restrict__ in_b,
            const float* __restrict__ h_W,
            const float* __restrict__ S,   // raw per-chunk sums [B,C,H]
            float* __restrict__ Q) {       // [HQ][B][D] partial dots
    int blk = blockIdx.x;
    int bg  = blk >> 7;
    int chq = blk & 127;
    int c   = (C - 1) - (chq >> 2);   // reversed: big-prefix blocks first
    int hq  = chq & 3;
    int b0  = bg * BG;
    int tid = threadIdx.x;
    int h   = hq * HP + tid;
    int lane = tid & 63;
    int wv = tid >> 6;
    int ph = lane & 3;

    __shared__ float wt[L][HP + 2];
    __shared__ float4 xs4[L];
    __shared__ float red[4][BG][L];

    if (tid < L) {
        int i = c * L + tid;
        xs4[tid] = make_float4(x[(size_t)b0 * D + i],
                               x[(size_t)(b0 + 1) * D + i],
                               x[(size_t)(b0 + 2) * D + i],
                               x[(size_t)(b0 + 3) * D + i]);
    }
    load_wt_tile(in_W, hq, c, tid, wt);

    // fused exclusive prefix over chunks (coalesced loads, independent adds)
    float ib = in_b[h];
    float a0 = ib, a1 = ib, a2 = ib, a3 = ib;
    #pragma unroll 4
    for (int cc = 0; cc < c; ++cc) {
        a0 += S[((size_t)b0 * C + cc) * H + h];
        a1 += S[((size_t)(b0 + 1) * C + cc) * H + h];
        a2 += S[((size_t)(b0 + 2) * C + cc) * H + h];
        a3 += S[((size_t)(b0 + 3) * C + cc) * H + h];
    }

    __syncthreads();

    bool k0 = (ph == 0), k1 = (ph == 1), k2 = (ph == 2), k3 = (ph == 3);

    float pr0[8], pr1[8], pr2[8], pr3[8];
    #pragma unroll
    for (int s = 0; s < 8; ++s) { pr0[s] = 0.f; pr1[s] = 0.f; pr2[s] = 0.f; pr3[s] = 0.f; }

    #pragma unroll
    for (int il = 0; il < L; ++il) {
        int i = c * L + il;
        float w  = h_W[(size_t)i * H + h];
        float wtv = wt[il][tid];
        float4 xf = xs4[il];
        int s = il >> 2;
        bool keep = (il & 3) == 0 ? k0 : ((il & 3) == 1 ? k1 : ((il & 3) == 2 ? k2 : k3));

        float p0 = fmaxf(a0, 0.f) * w;
        float t0 = p0 + dpp_xor1(p0); t0 = t0 + dpp_xor2(t0);
        pr0[s] = keep ? t0 : pr0[s];
        a0 = fmaf(xf.x, wtv, a0);

        float p1 = fmaxf(a1, 0.f) * w;
        float t1 = p1 + dpp_xor1(p1); t1 = t1 + dpp_xor2(t1);
        pr1[s] = keep ? t1 : pr1[s];
        a1 = fmaf(xf.y, wtv, a1);

        float p2 = fmaxf(a2, 0.f) * w;
        float t2 = p2 + dpp_xor1(p2); t2 = t2 + dpp_xor2(t2);
        pr2[s] = keep ? t2 : pr2[s];
        a2 = fmaf(xf.z, wtv, a2);

        float p3 = fmaxf(a3, 0.f) * w;
        float t3 = p3 + dpp_xor1(p3); t3 = t3 + dpp_xor2(t3);
        pr3[s] = keep ? t3 : pr3[s];
        a3 = fmaf(xf.w, wtv, a3);
    }

    // cross-quad reduce within the wave (sum over 16 quads = 64 h)
    #pragma unroll
    for (int s = 0; s < 8; ++s) {
        float v;
        v = pr0[s];
        v += __shfl_xor(v, 4, 64); v += __shfl_xor(v, 8, 64);
        v += __shfl_xor(v, 16, 64); v += __shfl_xor(v, 32, 64);
        pr0[s] = v;
        v = pr1[s];
        v += __shfl_xor(v, 4, 64); v += __shfl_xor(v, 8, 64);
        v += __shfl_xor(v, 16, 64); v += __shfl_xor(v, 32, 64);
        pr1[s] = v;
        v = pr2[s];
        v += __shfl_xor(v, 4, 64); v += __shfl_xor(v, 8, 64);
        v += __shfl_xor(v, 16, 64); v += __shfl_xor(v, 32, 64);
        pr2[s] = v;
        v = pr3[s];
        v += __shfl_xor(v, 4, 64); v += __shfl_xor(v, 8, 64);
        v += __shfl_xor(v, 16, 64); v += __shfl_xor(v, 32, 64);
        pr3[s] = v;
    }

    if (lane < 4) {
        #pragma unroll
        for (int s = 0; s < 8; ++s) {
            red[wv][0][s * 4 + lane] = pr0[s];
            red[wv][1][s * 4 + lane] = pr1[s];
            red[wv][2][s * 4 + lane] = pr2[s];
            red[wv][3][s * 4 + lane] = pr3[s];
        }
    }
    __syncthreads();

    if (tid < BG * L) {
        int b = tid >> 5;
        int il = tid & 31;
        float t = red[0][b][il] + red[1][b][il] + red[2][b][il] + red[3][b][il];
        Q[((size_t)hq * B + (b0 + b)) * D + c * L + il] = t;
    }
}

// ---------------------------------------------------------------------------
// Kernel 3: combine h-quarter partials + bias + sigmoid
// ---------------------------------------------------------------------------
__global__ void __launch_bounds__(256)
k_combine(const float* __restrict__ Q,
          const float* __restrict__ h_b,
          float* __restrict__ out) {
    int idx = blockIdx.x * blockDim.x + threadIdx.x;  // 0 .. B*D-1
    if (idx >= B * D) return;
    int d = idx & (D - 1);
    float t = Q[idx] + Q[(size_t)B * D + idx] + Q[2 * (size_t)B * D + idx]
            + Q[3 * (size_t)B * D + idx] + h_b[d];
    out[idx] = 1.0f / (1.0f + expf(-t));
}

// ---------------------------------------------------------------------------
extern "C" void kernel_launch(void* const* d_in, const int* in_sizes, int n_in,
                              void* d_out, int out_size, void* d_ws, size_t ws_size,
                              hipStream_t stream) {
    const float* x    = (const float*)d_in[0];  // [B, D]
    const float* in_W = (const float*)d_in[1];  // [H, D]
    const float* in_b = (const float*)d_in[2];  // [H]
    const float* h_W  = (const float*)d_in[3];  // [D, H]
    const float* h_b  = (const float*)d_in[4];  // [D]
    float* out = (float*)d_out;                 // [B, D]

    float* S = (float*)d_ws;                    // [B, C, H]   8 MB
    float* Q = S + (size_t)B * C * H;           // [HQ, B, D]  1 MB

    // 1: chunk sums (LDS-transposed weight tile, BG=4 register reuse)
    k_chunk_sums<<<NBG * C * HQ, 256, 0, stream>>>(x, in_W, S);

    // 2: main chain (LDS-transposed tile + fused prefix scan)
    k_nade_main<<<NBG * C * HQ, 256, 0, stream>>>(x, in_W, in_b, h_W, S, Q);

    // 3: combine quarters + sigmoid
    k_combine<<<(B * D + 255) / 256, 256, 0, stream>>>(Q, h_b, out);
}